// Round 1
// baseline (9101.758 us; speedup 1.0000x reference)
//
#include <hip/hip_runtime.h>
#include <math.h>

// Problem constants (from reference)
#define DD 128        // D
#define HH 256        // H
#define NS 300        // NUM_STEPS
#define BB 512        // B
#define RR 4          // rows (trajectories) per block
#define NB (BB / RR)  // 128 blocks

__device__ __forceinline__ float tsf(int t) {
    // ts = linspace(0, 1, NS+1)
    return (float)((double)t * (1.0 / (double)NS));
}

__device__ __forceinline__ float wave_red(float v) {
#pragma unroll
    for (int o = 32; o > 0; o >>= 1) v += __shfl_down(v, o);
    return v;
}

// ---- shared helpers -------------------------------------------------------
// MLP: h = tanh([t,x] @ W1 + b1); nv = h @ W2 + b2.
// 256 threads: h-phase thread j = hidden col; nv-phase thread = (i = j&127, kh = j>>7).
// Leaves nvs[r][i] written (writer == reader mapping for (r,i)); NO trailing barrier.
__device__ __forceinline__ void mlp_eval(
    const float* __restrict__ W1, const float* __restrict__ W2,
    float b1j, float b2i, float t0, int j, int i, int kh,
    const float (*xs)[132], float (*hs)[HH],
    float (*pv)[RR][DD], float (*nvs)[DD], float* nv_out)
{
    float acc[RR];
    {
        const float w0 = W1[j];  // W1 row 0 is the time input
#pragma unroll
        for (int r = 0; r < RR; ++r) acc[r] = t0 * w0;
    }
    for (int k4 = 0; k4 < DD; k4 += 4) {
        const float w0 = W1[(k4 + 1) * HH + j];
        const float w1 = W1[(k4 + 2) * HH + j];
        const float w2 = W1[(k4 + 3) * HH + j];
        const float w3 = W1[(k4 + 4) * HH + j];
#pragma unroll
        for (int r = 0; r < RR; ++r) {
            const float4 xv = *(const float4*)&xs[r][k4];
            acc[r] = fmaf(xv.w, w3, fmaf(xv.z, w2, fmaf(xv.y, w1, fmaf(xv.x, w0, acc[r]))));
        }
    }
#pragma unroll
    for (int r = 0; r < RR; ++r) hs[r][j] = tanhf(acc[r] + b1j);
    __syncthreads();

    float a2[RR];
#pragma unroll
    for (int r = 0; r < RR; ++r) a2[r] = 0.f;
    const int kb = kh * 128;
    for (int k4 = kb; k4 < kb + 128; k4 += 4) {
        const float w0 = W2[(k4 + 0) * DD + i];
        const float w1 = W2[(k4 + 1) * DD + i];
        const float w2 = W2[(k4 + 2) * DD + i];
        const float w3 = W2[(k4 + 3) * DD + i];
#pragma unroll
        for (int r = 0; r < RR; ++r) {
            const float4 hv = *(const float4*)&hs[r][k4];
            a2[r] = fmaf(hv.w, w3, fmaf(hv.z, w2, fmaf(hv.y, w1, fmaf(hv.x, w0, a2[r]))));
        }
    }
#pragma unroll
    for (int r = 0; r < RR; ++r) pv[kh][r][i] = a2[r];
    __syncthreads();
#pragma unroll
    for (int p = 0; p < 2; ++p) {
        const int r = kh + 2 * p;
        const float nv = pv[0][r][i] + pv[1][r][i] + b2i;
        nvs[r][i] = nv;
        nv_out[p] = nv;
    }
}

// Half-split 128->128 matvec partial: pvq[kh][r][i] = sum_{k in kh-half} M[k*DD+i]*v[r][k]
__device__ __forceinline__ void halfmat(
    const float* __restrict__ M, const float (*v)[DD],
    int i, int kh, float (*pvq)[RR][DD])
{
    float a[RR];
#pragma unroll
    for (int r = 0; r < RR; ++r) a[r] = 0.f;
    const int kb = kh * 64;
    for (int k4 = kb; k4 < kb + 64; k4 += 4) {
        const float m0 = M[(k4 + 0) * DD + i];
        const float m1 = M[(k4 + 1) * DD + i];
        const float m2 = M[(k4 + 2) * DD + i];
        const float m3 = M[(k4 + 3) * DD + i];
#pragma unroll
        for (int r = 0; r < RR; ++r) {
            const float4 vv = *(const float4*)&v[r][k4];
            a[r] = fmaf(vv.w, m3, fmaf(vv.z, m2, fmaf(vv.y, m1, fmaf(vv.x, m0, a[r]))));
        }
    }
#pragma unroll
    for (int r = 0; r < RR; ++r) pvq[kh][r][i] = a[r];
}

// Same but source is the 132-stride xs buffer
__device__ __forceinline__ void half_from_xs(
    const float* __restrict__ M, const float (*xs)[132],
    int i, int kh, float (*pvq)[RR][DD])
{
    float a[RR];
#pragma unroll
    for (int r = 0; r < RR; ++r) a[r] = 0.f;
    const int kb = kh * 64;
    for (int k4 = kb; k4 < kb + 64; k4 += 4) {
        const float m0 = M[(k4 + 0) * DD + i];
        const float m1 = M[(k4 + 1) * DD + i];
        const float m2 = M[(k4 + 2) * DD + i];
        const float m3 = M[(k4 + 3) * DD + i];
#pragma unroll
        for (int r = 0; r < RR; ++r) {
            const float4 xv = *(const float4*)&xs[r][k4];
            a[r] = fmaf(xv.w, m3, fmaf(xv.z, m2, fmaf(xv.y, m1, fmaf(xv.x, m0, a[r]))));
        }
    }
#pragma unroll
    for (int r = 0; r < RR; ++r) pvq[kh][r][i] = a[r];
}

// ---- precompute: transposes, identity flag, (general) sigma^-T and M2 -----
__global__ __launch_bounds__(256) void k_precompute(
    const float* __restrict__ sigma, const float* __restrict__ A,
    const float* __restrict__ P, const float* __restrict__ Q,
    float* __restrict__ AT, float* __restrict__ PT, float* __restrict__ QT,
    float* __restrict__ SGT, float* __restrict__ SIT, float* __restrict__ M2T,
    float* __restrict__ AUG, int* __restrict__ FLG)
{
    const int j = threadIdx.x;
    __shared__ int s_ok;
    __shared__ int s_p;
    __shared__ float s_fac[DD];
    if (j == 0) s_ok = 1;
    __syncthreads();
    bool ok = true;
    for (int idx = j; idx < DD * DD; idx += 256) {
        const int r = idx >> 7, c = idx & (DD - 1);
        if (sigma[idx] != (r == c ? 1.f : 0.f)) ok = false;
    }
    if (!ok) s_ok = 0;
    __syncthreads();
    const bool ident = (s_ok != 0);
    if (j == 0) *FLG = ident ? 1 : 0;

    for (int idx = j; idx < DD * DD; idx += 256) {
        const int k = idx >> 7, i2 = idx & (DD - 1);
        AT[idx]  = A[i2 * DD + k];
        PT[idx]  = P[i2 * DD + k];
        QT[idx]  = Q[i2 * DD + k];
        SGT[idx] = sigma[i2 * DD + k];
    }
    if (ident) {
        for (int idx = j; idx < DD * DD; idx += 256) {
            const int k = idx >> 7, i2 = idx & (DD - 1);
            M2T[idx] = -A[i2 * DD + k];      // M2 = -A @ I
            SIT[idx] = (k == i2) ? 1.f : 0.f;
        }
    } else {
        // Gauss-Jordan with partial pivoting in global scratch AUG[128][256]
        for (int idx = j; idx < DD * 256; idx += 256) {
            const int r = idx >> 8, c = idx & 255;
            AUG[idx] = (c < DD) ? sigma[r * DD + c] : ((c - DD) == r ? 1.f : 0.f);
        }
        __syncthreads();
        for (int c = 0; c < DD; ++c) {
            if (j == 0) {
                int p = c; float best = fabsf(AUG[c * 256 + c]);
                for (int r2 = c + 1; r2 < DD; ++r2) {
                    const float v = fabsf(AUG[r2 * 256 + c]);
                    if (v > best) { best = v; p = r2; }
                }
                s_p = p;
            }
            __syncthreads();
            const int p = s_p;
            if (p != c) {
                const float tmp = AUG[c * 256 + j];
                AUG[c * 256 + j] = AUG[p * 256 + j];
                AUG[p * 256 + j] = tmp;
            }
            __syncthreads();
            const float pd = AUG[c * 256 + c];
            const float rowv = AUG[c * 256 + j];
            __syncthreads();
            AUG[c * 256 + j] = rowv / pd;
            if (j < DD) s_fac[j] = (j == c) ? 0.f : AUG[j * 256 + c];
            __syncthreads();
            const float prj = AUG[c * 256 + j];
            for (int r2 = 0; r2 < DD; ++r2) {
                if (r2 != c) AUG[r2 * 256 + j] -= s_fac[r2] * prj;
            }
            __syncthreads();
        }
        // SIT[k*DD+i] = sigma^-T[k][i] = inv[i][k]
        for (int idx = j; idx < DD * DD; idx += 256) {
            const int k = idx >> 7, i2 = idx & (DD - 1);
            SIT[idx] = AUG[i2 * 256 + DD + k];
        }
        __syncthreads();
        // M2T[j2*DD+i] = M2[i][j2] = -sum_k A[i][k] * sigma^-T[k][j2]
        for (int idx = j; idx < DD * DD; idx += 256) {
            const int j2 = idx >> 7, i2 = idx & (DD - 1);
            float acc = 0.f;
            for (int k = 0; k < DD; ++k) acc = fmaf(A[i2 * DD + k], SIT[k * DD + j2], acc);
            M2T[idx] = -acc;
        }
    }
}

// ---- phase 1: rollout -----------------------------------------------------
__global__ __launch_bounds__(256) void k_rollout(
    const float* __restrict__ x0, const float* __restrict__ sigma,
    const float* __restrict__ W1, const float* __restrict__ b1,
    const float* __restrict__ W2, const float* __restrict__ b2,
    const float* __restrict__ noises,
    const float* __restrict__ AT, const float* __restrict__ PT,
    const float* __restrict__ SGT, const int* __restrict__ FLG,
    float* __restrict__ S, float* __restrict__ LW)
{
    __shared__ float xs[RR][132];
    __shared__ float hs[RR][HH];
    __shared__ float nvs[RR][DD];
    __shared__ float uu[RR][DD];
    __shared__ float noi[RR][DD];
    __shared__ float pv4[4][2][RR][DD];
    __shared__ float red[4][2];
    const int j = threadIdx.x;
    const int b0 = blockIdx.x * RR;
    const int i = j & (DD - 1);
    const int kh = j >> 7;
    const int wid = j >> 6;
    const bool ident = (*FLG != 0);
    const float b1j = b1[j];
    const float b2i = b2[i];
    float lwloc[2] = {0.f, 0.f};

    for (int idx = j; idx < RR * DD; idx += 256) {
        const int r = idx >> 7, ii = idx & (DD - 1);
        const float v = x0[ii];
        xs[r][ii] = v;
        S[(size_t)(b0 + r) * DD + ii] = v;   // states[0]
    }

    for (int t = 0; t < NS; ++t) {
        __syncthreads(); // [A]
        const float t0 = tsf(t);
        const float dt = tsf(t + 1) - t0;
        const float sdt = sqrtf(dt);
        {
            const size_t nb_ = ((size_t)t * BB + b0) * DD;
            for (int idx = j; idx < RR * DD; idx += 256)
                noi[idx >> 7][idx & (DD - 1)] = noises[nb_ + idx];
        }
        float nvo[2];
        mlp_eval(W1, W2, b1j, b2i, t0, j, i, kh, xs, hs, pv4[0], nvs, nvo);
#pragma unroll
        for (int p = 0; p < 2; ++p) uu[kh + 2 * p][i] = -nvo[p]; // identity u
        __syncthreads(); // [D]
        if (!ident) {
            halfmat(sigma, nvs, i, kh, pv4[1]);  // u = -nv @ sigma
            __syncthreads();
#pragma unroll
            for (int p = 0; p < 2; ++p) {
                const int r = kh + 2 * p;
                uu[r][i] = -(pv4[1][0][r][i] + pv4[1][1][r][i]);
            }
            __syncthreads();
        }
        half_from_xs(AT, xs, i, kh, pv4[0]);   // x @ A^T
        half_from_xs(PT, xs, i, kh, pv4[1]);   // P @ x (for f_val)
        if (!ident) {
            halfmat(SGT, noi, i, kh, pv4[2]);  // noise @ sigma^T
            halfmat(SGT, uu,  i, kh, pv4[3]);  // u @ sigma^T
        }
        __syncthreads(); // [E]
#pragma unroll
        for (int p = 0; p < 2; ++p) {
            const int r = kh + 2 * p;
            const float xo = xs[r][i];
            const float xa = pv4[0][0][r][i] + pv4[0][1][r][i];
            const float yy = pv4[1][0][r][i] + pv4[1][1][r][i];
            const float ui = uu[r][i];
            const float nz = noi[r][i];
            const float nsv = ident ? nz : (pv4[2][0][r][i] + pv4[2][1][r][i]);
            const float usv = ident ? ui : (pv4[3][0][r][i] + pv4[3][1][r][i]);
            const float xn = xo + (xa + usv) * dt + sdt * nsv;
            xs[r][i] = xn;
            S[((size_t)(t + 1) * BB + b0 + r) * DD + i] = xn;
            // lw_det + lw_sto contribution of index i
            lwloc[p] += sdt * ui * nz - dt * (0.5f * ui * ui + 0.5f * xo * yy);
        }
    }
    __syncthreads();
    {
        const float v0 = wave_red(lwloc[0]);
        const float v1 = wave_red(lwloc[1]);
        if ((j & 63) == 0) { red[wid][0] = v0; red[wid][1] = v1; }
        __syncthreads();
        if (j < RR) {
            const int r = j, p = r >> 1, khr = r & 1;
            LW[b0 + r] = red[2 * khr][p] + red[2 * khr + 1][p];
        }
    }
}

// ---- phase 2: backward scan + objective -----------------------------------
__global__ __launch_bounds__(256) void k_backward(
    const float* __restrict__ sigma,
    const float* __restrict__ W1, const float* __restrict__ b1,
    const float* __restrict__ W2, const float* __restrict__ b2,
    const float* __restrict__ noises,
    const float* __restrict__ PT, const float* __restrict__ QT,
    const float* __restrict__ M2T, const int* __restrict__ FLG,
    const float* __restrict__ S, const float* __restrict__ LW,
    float* __restrict__ PART)
{
    __shared__ float xs[RR][132];
    __shared__ float hs[RR][HH];
    __shared__ float nvs[RR][DD];
    __shared__ float uu[RR][DD];
    __shared__ float noi[RR][DD];
    __shared__ float wvv[RR][DD];
    __shared__ float lst[RR][DD];
    __shared__ float ddm[RR][DD];
    __shared__ float pv4[3][2][RR][DD];
    __shared__ float red[4][2];
    __shared__ float wgt[RR];
    __shared__ float robj[4];
    const int j = threadIdx.x;
    const int b0 = blockIdx.x * RR;
    const int i = j & (DD - 1);
    const int kh = j >> 7;
    const int wid = j >> 6;
    const bool ident = (*FLG != 0);
    const float b1j = b1[j];
    const float b2i = b2[i];
    float objloc = 0.f;

    for (int t = NS; t >= 0; --t) {
        __syncthreads(); // [A]
        {
            const size_t xb = ((size_t)t * BB + b0) * DD;
            for (int idx = j; idx < RR * DD; idx += 256)
                xs[idx >> 7][idx & (DD - 1)] = S[xb + idx];
            if (t < NS) {
                const size_t nb_ = ((size_t)t * BB + b0) * DD;
                for (int idx = j; idx < RR * DD; idx += 256)
                    noi[idx >> 7][idx & (DD - 1)] = noises[nb_ + idx];
            }
        }
        const float t0 = tsf(t);
        const float dt = (t < NS) ? (tsf(t + 1) - t0) : 0.f;
        const float sdt = sqrtf(dt);
        __syncthreads(); // [B]
        float nvo[2];
        mlp_eval(W1, W2, b1j, b2i, t0, j, i, kh, xs, hs, pv4[0], nvs, nvo);

        if (t == NS) {
            half_from_xs(QT, xs, i, kh, pv4[1]);  // target_terminal = x_T @ Q^T
            __syncthreads();
            float lg0 = 0.f, lg1 = 0.f;
#pragma unroll
            for (int p = 0; p < 2; ++p) {
                const int r = kh + 2 * p;
                const float tt = pv4[1][0][r][i] + pv4[1][1][r][i];
                lst[r][i] = tt;
                const float lg = xs[r][i] * tt;
                if (p == 0) lg0 = lg; else lg1 = lg;
            }
            const float g0 = wave_red(lg0);
            const float g1 = wave_red(lg1);
            if ((j & 63) == 0) { red[wid][0] = g0; red[wid][1] = g1; }
            __syncthreads();
            if (j < RR) {
                const int r = j, p = r >> 1, khr = r & 1;
                const float qf = red[2 * khr][p] + red[2 * khr + 1][p];
                wgt[r] = expf(LW[b0 + r] - 0.5f * qf);  // exp(lw_det+lw_sto+log_terminal)
            }
            __syncthreads();
            if (ident) {
#pragma unroll
                for (int p = 0; p < 2; ++p) {
                    const int r = kh + 2 * p;
                    const float d = lst[r][i] - nvs[r][i];
                    objloc += wgt[r] * d * d;
                }
            } else {
#pragma unroll
                for (int p = 0; p < 2; ++p) {
                    const int r = kh + 2 * p;
                    ddm[r][i] = lst[r][i] - nvs[r][i];
                }
                __syncthreads();
                halfmat(sigma, ddm, i, kh, pv4[2]);
                __syncthreads();
#pragma unroll
                for (int p = 0; p < 2; ++p) {
                    const int r = kh + 2 * p;
                    const float e = pv4[2][0][r][i] + pv4[2][1][r][i];
                    objloc += wgt[r] * e * e;
                }
            }
        } else {
            if (ident) {
#pragma unroll
                for (int p = 0; p < 2; ++p) {
                    const int r = kh + 2 * p;
                    uu[r][i] = -nvo[p];
                    wvv[r][i] = sdt * noi[r][i] - dt * nvo[p];  // sqrt(dt)*noise + dt*u
                }
                __syncthreads();
            } else {
                __syncthreads();
                halfmat(sigma, nvs, i, kh, pv4[1]);  // u = -nv @ sigma
                __syncthreads();
#pragma unroll
                for (int p = 0; p < 2; ++p) {
                    const int r = kh + 2 * p;
                    const float ui = -(pv4[1][0][r][i] + pv4[1][1][r][i]);
                    uu[r][i] = ui;
                    wvv[r][i] = sdt * noi[r][i] + dt * ui;
                }
                __syncthreads();
            }
            half_from_xs(PT, xs, i, kh, pv4[0]);  // P @ x
            halfmat(M2T, wvv, i, kh, pv4[1]);     // M2 @ (sqrt(dt)*noise + dt*u)
            __syncthreads();
            if (ident) {
#pragma unroll
                for (int p = 0; p < 2; ++p) {
                    const int r = kh + 2 * p;
                    const float yy = pv4[0][0][r][i] + pv4[0][1][r][i];
                    const float mv = pv4[1][0][r][i] + pv4[1][1][r][i];
                    const float l = lst[r][i] + dt * yy + mv;
                    lst[r][i] = l;
                    const float d = l - nvs[r][i];
                    objloc += wgt[r] * d * d;
                }
            } else {
#pragma unroll
                for (int p = 0; p < 2; ++p) {
                    const int r = kh + 2 * p;
                    const float yy = pv4[0][0][r][i] + pv4[0][1][r][i];
                    const float mv = pv4[1][0][r][i] + pv4[1][1][r][i];
                    const float l = lst[r][i] + dt * yy + mv;
                    lst[r][i] = l;
                    ddm[r][i] = l - nvs[r][i];
                }
                __syncthreads();
                halfmat(sigma, ddm, i, kh, pv4[2]);  // sigma^T (lst - nabla_V)
                __syncthreads();
#pragma unroll
                for (int p = 0; p < 2; ++p) {
                    const int r = kh + 2 * p;
                    const float e = pv4[2][0][r][i] + pv4[2][1][r][i];
                    objloc += wgt[r] * e * e;
                }
            }
        }
    }
    __syncthreads();
    {
        const float v = wave_red(objloc);
        if ((j & 63) == 0) robj[wid] = v;
        __syncthreads();
        if (j == 0) PART[blockIdx.x] = robj[0] + robj[1] + robj[2] + robj[3];
    }
}

__global__ void k_finalize(const float* __restrict__ PART, float* __restrict__ out)
{
    const int j = threadIdx.x; // 128 threads
    __shared__ float rr[2];
    float v = (j < NB) ? PART[j] : 0.f;
    v = wave_red(v);
    if ((j & 63) == 0) rr[j >> 6] = v;
    __syncthreads();
    if (j == 0) out[0] = (rr[0] + rr[1]) * (1.0f / ((float)(NS + 1) * (float)BB));
}

extern "C" void kernel_launch(void* const* d_in, const int* in_sizes, int n_in,
                              void* d_out, int out_size, void* d_ws, size_t ws_size,
                              hipStream_t stream) {
    (void)in_sizes; (void)n_in; (void)out_size; (void)ws_size;
    const float* x0     = (const float*)d_in[0];
    const float* sigma  = (const float*)d_in[1];
    const float* A      = (const float*)d_in[2];
    const float* P      = (const float*)d_in[3];
    const float* Q      = (const float*)d_in[4];
    const float* W1     = (const float*)d_in[5];
    const float* b1     = (const float*)d_in[6];
    const float* W2     = (const float*)d_in[7];
    const float* b2     = (const float*)d_in[8];
    const float* noises = (const float*)d_in[9];

    float* ws  = (float*)d_ws;
    float* S   = ws;                                  // (NS+1)*B*D
    float* LW  = S + (size_t)(NS + 1) * BB * DD;      // B
    float* AT  = LW + BB;
    float* PT  = AT + DD * DD;
    float* QT  = PT + DD * DD;
    float* SGT = QT + DD * DD;
    float* SIT = SGT + DD * DD;
    float* M2T = SIT + DD * DD;
    float* AUG = M2T + DD * DD;                       // 128*256 GJ scratch
    float* PART = AUG + DD * 256;                     // NB partials
    int*   FLG = (int*)(PART + NB);
    float* out = (float*)d_out;

    k_precompute<<<1, 256, 0, stream>>>(sigma, A, P, Q, AT, PT, QT, SGT, SIT, M2T, AUG, FLG);
    k_rollout<<<NB, 256, 0, stream>>>(x0, sigma, W1, b1, W2, b2, noises, AT, PT, SGT, FLG, S, LW);
    k_backward<<<NB, 256, 0, stream>>>(sigma, W1, b1, W2, b2, noises, PT, QT, M2T, FLG, S, LW, PART);
    k_finalize<<<1, 128, 0, stream>>>(PART, out);
}

// Round 2
// 2723.671 us; speedup vs baseline: 3.3417x; 3.3417x over previous
//
#include <hip/hip_runtime.h>
#include <math.h>

#define DD 128
#define HH 256
#define NS 300
#define BB 512
#define NBLK 256   // rollout blocks (2 rows each)
#define TPB 512
#define NPO (301*64)

__device__ __forceinline__ float tsf(int t){ return (float)((double)t*(1.0/(double)NS)); }

__device__ __forceinline__ float wave_red(float v){
#pragma unroll
  for(int o=32;o>0;o>>=1) v += __shfl_down(v,o);
  return v;
}
__device__ __forceinline__ float fma4(float4 a, float4 b, float acc){
  acc = fmaf(a.x,b.x,acc); acc = fmaf(a.y,b.y,acc);
  acc = fmaf(a.z,b.z,acc); acc = fmaf(a.w,b.w,acc); return acc;
}

// ---- pre1: identity flag + (general) Gauss-Jordan inverse -> SIT = sigma^-T
__global__ __launch_bounds__(256) void k_pre1(
    const float* __restrict__ sigma,
    float* __restrict__ SIT, float* __restrict__ AUG, int* __restrict__ FLG)
{
  const int j = threadIdx.x;
  __shared__ int s_ok; __shared__ int s_p; __shared__ float s_fac[DD];
  if (j == 0) s_ok = 1;
  __syncthreads();
  bool ok = true;
  for (int idx = j; idx < DD*DD; idx += 256) {
    const int r = idx >> 7, c = idx & 127;
    if (sigma[idx] != (r==c ? 1.f : 0.f)) ok = false;
  }
  if (!ok) s_ok = 0;
  __syncthreads();
  const bool ident = (s_ok != 0);
  if (j == 0) *FLG = ident ? 1 : 0;
  if (ident) {
    for (int idx = j; idx < DD*DD; idx += 256) {
      const int r = idx >> 7, c = idx & 127;
      SIT[idx] = (r==c) ? 1.f : 0.f;
    }
    return;
  }
  for (int idx = j; idx < DD*256; idx += 256) {
    const int r = idx >> 8, c = idx & 255;
    AUG[idx] = (c < DD) ? sigma[r*DD + c] : ((c-DD)==r ? 1.f : 0.f);
  }
  __syncthreads();
  for (int c = 0; c < DD; ++c) {
    if (j == 0) {
      int p = c; float best = fabsf(AUG[c*256 + c]);
      for (int r2 = c+1; r2 < DD; ++r2) {
        const float v = fabsf(AUG[r2*256 + c]);
        if (v > best) { best = v; p = r2; }
      }
      s_p = p;
    }
    __syncthreads();
    const int p = s_p;
    if (p != c) {
      const float tmp = AUG[c*256 + j];
      AUG[c*256 + j] = AUG[p*256 + j];
      AUG[p*256 + j] = tmp;
    }
    __syncthreads();
    const float pd = AUG[c*256 + c];
    const float rowv = AUG[c*256 + j];
    __syncthreads();
    AUG[c*256 + j] = rowv / pd;
    if (j < DD) s_fac[j] = (j == c) ? 0.f : AUG[j*256 + c];
    __syncthreads();
    const float prj = AUG[c*256 + j];
    for (int r2 = 0; r2 < DD; ++r2) {
      if (r2 != c) AUG[r2*256 + j] -= s_fac[r2] * prj;
    }
    __syncthreads();
  }
  // SIT[j2][k] = sigma^-T[j2][k] = inv[k][j2]
  for (int idx = j; idx < DD*DD; idx += 256) {
    const int j2 = idx >> 7, k = idx & 127;
    SIT[idx] = AUG[k*256 + DD + j2];
  }
}

// ---- pre2: weight transposes + M2 rows + sigma^T rows
__global__ __launch_bounds__(256) void k_pre2(
    const float* __restrict__ W1, const float* __restrict__ W2,
    const float* __restrict__ A, const float* __restrict__ sigma,
    const float* __restrict__ SIT, const int* __restrict__ FLG,
    float* __restrict__ W1Tt, float* __restrict__ W1Tx,
    float* __restrict__ W2T, float* __restrict__ M2row,
    float* __restrict__ SG2row)
{
  const int g = blockIdx.x*256 + threadIdx.x;
  const int gs = gridDim.x*256;
  const bool ident = (*FLG != 0);
  for (int idx = g; idx < HH; idx += gs) W1Tt[idx] = W1[idx];   // time row
  for (int idx = g; idx < HH*DD; idx += gs) {
    const int hj = idx >> 7, kk = idx & 127;
    W1Tx[idx] = W1[(kk+1)*HH + hj];
  }
  for (int idx = g; idx < DD*HH; idx += gs) {
    const int i2 = idx >> 8, k = idx & 255;
    W2T[idx] = W2[k*DD + i2];
  }
  for (int idx = g; idx < DD*DD; idx += gs) {
    const int i2 = idx >> 7, k = idx & 127;
    SG2row[idx] = sigma[k*DD + i2];
    float m;
    if (ident) m = -A[i2*DD + k];
    else {
      float acc = 0.f;
      for (int j = 0; j < DD; ++j) acc = fmaf(A[i2*DD + j], SIT[j*DD + k], acc);
      m = -acc;
    }
    M2row[idx] = m;
  }
}

// ---- rollout: 256 blocks x 512 threads, 2 trajectories per block.
// Produces U (controls, t=0..NS), TERM slices (TL[1..NS]), TGT, WGT.
__global__ __launch_bounds__(TPB, 2) void k_rollout(
    const float* __restrict__ x0, const float* __restrict__ sigma,
    const float* __restrict__ W1Tt, const float* __restrict__ W1Tx,
    const float* __restrict__ W2T,
    const float* __restrict__ b1, const float* __restrict__ b2,
    const float* __restrict__ noises,
    const float* __restrict__ A, const float* __restrict__ P,
    const float* __restrict__ Qm,
    const float* __restrict__ M2row, const float* __restrict__ SG2row,
    const int* __restrict__ FLG,
    float* __restrict__ U, float* __restrict__ TL,
    float* __restrict__ TGT, float* __restrict__ WGT)
{
  __shared__ __align__(16) float xs[2][132];
  __shared__ __align__(16) float hs[2][256];
  __shared__ __align__(16) float p2[2][2][256];
  __shared__ __align__(16) float p4[4][2][128];
  __shared__ __align__(16) float pA[4][2][128];
  __shared__ __align__(16) float pP[4][2][128];
  __shared__ __align__(16) float pM[4][2][128];
  __shared__ __align__(16) float pUs[4][2][128];
  __shared__ __align__(16) float pNs[4][2][128];
  __shared__ __align__(16) float nvs[2][128];
  __shared__ __align__(16) float uu[2][128];
  __shared__ __align__(16) float noi[2][128];
  __shared__ __align__(16) float wv[2][128];
  __shared__ float red1[8], red2[8];

  const int tid = threadIdx.x;
  const int hj = tid & 255, hg = tid >> 8;
  const int i = tid & 127, q = tid >> 7;
  const int wid = tid >> 6;
  const int b0 = blockIdx.x * 2;
  const bool ident = (*FLG != 0);
  const float b1j = b1[hj];
  const float b2i = b2[i];
  const float* w1row = W1Tx + hj*128 + hg*64;
  const float* w2row = W2T + i*256 + q*64;
  const float w1t = (hg == 0) ? W1Tt[hj] : 0.f;
  float lwloc = 0.f;

  if (q < 2) xs[q][i] = x0[i];

  for (int t = 0; t <= NS; ++t) {
    __syncthreads();                                   // [A] xs ready
    const float t0 = tsf(t);
    const float dt = tsf(t+1) - t0;
    const float sdt = sqrtf(dt);
    float nz = 0.f;
    if (q < 2 && t < NS) nz = noises[((size_t)t*BB + b0 + q)*DD + i];
    if (q < 2) noi[q][i] = nz;
    // --- MLP layer 1: thread (hj, hg) accumulates over its input half
    float a0 = t0*w1t, a1 = t0*w1t;
#pragma unroll
    for (int it = 0; it < 16; ++it) {
      float4 w  = *(const float4*)(w1row + it*4);
      float4 v0 = *(const float4*)&xs[0][hg*64 + it*4];
      float4 v1 = *(const float4*)&xs[1][hg*64 + it*4];
      a0 = fma4(w, v0, a0); a1 = fma4(w, v1, a1);
    }
    p2[hg][0][hj] = a0; p2[hg][1][hj] = a1;
    __syncthreads();                                   // [B]
    hs[hg][hj] = tanhf(p2[0][hg][hj] + p2[1][hg][hj] + b1j);
    __syncthreads();                                   // [C]
    // --- MLP layer 2: thread (i, q) over hidden quarter
    a0 = 0.f; a1 = 0.f;
#pragma unroll
    for (int it = 0; it < 16; ++it) {
      float4 w  = *(const float4*)(w2row + it*4);
      float4 h0 = *(const float4*)&hs[0][q*64 + it*4];
      float4 h1 = *(const float4*)&hs[1][q*64 + it*4];
      a0 = fma4(w, h0, a0); a1 = fma4(w, h1, a1);
    }
    p4[q][0][i] = a0; p4[q][1][i] = a1;
    __syncthreads();                                   // [D]
    float u_reg = 0.f;
    if (q < 2) {
      const int r = q;
      const float nv = p4[0][r][i]+p4[1][r][i]+p4[2][r][i]+p4[3][r][i] + b2i;
      if (ident) {
        u_reg = -nv;
        uu[r][i] = u_reg;
        wv[r][i] = sdt*nz + dt*u_reg;
        U[((size_t)t*BB + b0 + r)*DD + i] = u_reg;
      } else {
        nvs[r][i] = nv;
      }
    }
    __syncthreads();                                   // [D2]
    if (!ident) {
      // u = -nv @ sigma: (nv@sigma)[i] = sum_k nv[k]*sigma[k][i]
      float s0 = 0.f, s1 = 0.f;
      const float* grow = SG2row + i*128 + q*32;
#pragma unroll
      for (int it = 0; it < 8; ++it) {
        float4 gv = *(const float4*)(grow + it*4);
        float4 n0 = *(const float4*)&nvs[0][q*32 + it*4];
        float4 n1 = *(const float4*)&nvs[1][q*32 + it*4];
        s0 = fma4(gv, n0, s0); s1 = fma4(gv, n1, s1);
      }
      pM[q][0][i] = s0; pM[q][1][i] = s1;
      __syncthreads();                                 // [D3]
      if (q < 2) {
        const int r = q;
        const float ui = -(pM[0][r][i]+pM[1][r][i]+pM[2][r][i]+pM[3][r][i]);
        u_reg = ui;
        uu[r][i] = ui;
        wv[r][i] = sdt*noi[r][i] + dt*ui;
        U[((size_t)t*BB + b0 + r)*DD + i] = ui;
      }
      __syncthreads();                                 // [D4]
    }
    if (t == NS) break;
    // --- matvecs: x@A^T, P@x, M2@wv (+ general sigma^T matvecs)
    {
      float aA0=0,aA1=0,aP0=0,aP1=0,aM0=0,aM1=0;
      const float* arow = A     + i*128 + q*32;
      const float* prow = P     + i*128 + q*32;
      const float* mrow = M2row + i*128 + q*32;
#pragma unroll
      for (int it = 0; it < 8; ++it) {
        float4 av  = *(const float4*)(arow + it*4);
        float4 pv  = *(const float4*)(prow + it*4);
        float4 mv  = *(const float4*)(mrow + it*4);
        float4 x0v = *(const float4*)&xs[0][q*32 + it*4];
        float4 x1v = *(const float4*)&xs[1][q*32 + it*4];
        float4 w0v = *(const float4*)&wv[0][q*32 + it*4];
        float4 w1v = *(const float4*)&wv[1][q*32 + it*4];
        aA0 = fma4(av, x0v, aA0); aA1 = fma4(av, x1v, aA1);
        aP0 = fma4(pv, x0v, aP0); aP1 = fma4(pv, x1v, aP1);
        aM0 = fma4(mv, w0v, aM0); aM1 = fma4(mv, w1v, aM1);
      }
      pA[q][0][i]=aA0; pA[q][1][i]=aA1;
      pP[q][0][i]=aP0; pP[q][1][i]=aP1;
      pM[q][0][i]=aM0; pM[q][1][i]=aM1;
      if (!ident) {
        float s0=0,s1=0,n0a=0,n1a=0;
        const float* srow = sigma + i*128 + q*32;   // (v@sigma^T)[i] = sum_k v[k]*sigma[i][k]
#pragma unroll
        for (int it = 0; it < 8; ++it) {
          float4 sv = *(const float4*)(srow + it*4);
          float4 u0 = *(const float4*)&uu[0][q*32 + it*4];
          float4 u1 = *(const float4*)&uu[1][q*32 + it*4];
          float4 z0 = *(const float4*)&noi[0][q*32 + it*4];
          float4 z1 = *(const float4*)&noi[1][q*32 + it*4];
          s0  = fma4(sv,u0,s0);  s1  = fma4(sv,u1,s1);
          n0a = fma4(sv,z0,n0a); n1a = fma4(sv,z1,n1a);
        }
        pUs[q][0][i]=s0;  pUs[q][1][i]=s1;
        pNs[q][0][i]=n0a; pNs[q][1][i]=n1a;
      }
    }
    __syncthreads();                                   // [E]
    if (q < 2) {
      const int r = q;
      const float xo = xs[r][i];
      const float xa = pA[0][r][i]+pA[1][r][i]+pA[2][r][i]+pA[3][r][i];
      const float yy = pP[0][r][i]+pP[1][r][i]+pP[2][r][i]+pP[3][r][i];
      const float mm = pM[0][r][i]+pM[1][r][i]+pM[2][r][i]+pM[3][r][i];
      float usv, nsv;
      if (ident) { usv = u_reg; nsv = nz; }
      else {
        usv = pUs[0][r][i]+pUs[1][r][i]+pUs[2][r][i]+pUs[3][r][i];
        nsv = pNs[0][r][i]+pNs[1][r][i]+pNs[2][r][i]+pNs[3][r][i];
      }
      TL[(size_t)(t+1)*(BB*DD) + (b0 + r)*DD + i] = dt*yy + mm;   // TERM[t+1]
      xs[r][i] = xo + (xa + usv)*dt + sdt*nsv;
      lwloc += sdt*u_reg*nz - dt*(0.5f*u_reg*u_reg + 0.5f*xo*yy);
    }
  }
  // epilogue: TGT = x_NS @ Q^T, WGT = exp(lw - 0.5 x^T Q x)
  __syncthreads();
  {
    float g0 = 0.f, g1 = 0.f;
    const float* qrow = Qm + i*128 + q*32;
#pragma unroll
    for (int it = 0; it < 8; ++it) {
      float4 qv  = *(const float4*)(qrow + it*4);
      float4 x0v = *(const float4*)&xs[0][q*32 + it*4];
      float4 x1v = *(const float4*)&xs[1][q*32 + it*4];
      g0 = fma4(qv, x0v, g0); g1 = fma4(qv, x1v, g1);
    }
    pA[q][0][i] = g0; pA[q][1][i] = g1;
  }
  __syncthreads();
  float qloc = 0.f;
  if (q < 2) {
    const int r = q;
    const float tt = pA[0][r][i]+pA[1][r][i]+pA[2][r][i]+pA[3][r][i];
    TGT[(b0 + r)*DD + i] = tt;
    qloc = xs[r][i]*tt;
  }
  const float rq = wave_red(qloc);
  const float rl = wave_red(lwloc);
  if ((tid & 63) == 0) { red1[wid] = rq; red2[wid] = rl; }
  __syncthreads();
  if (tid < 2) {
    const float qf = red1[2*tid] + red1[2*tid+1];
    const float lw = red2[2*tid] + red2[2*tid+1];
    WGT[b0 + tid] = expf(lw - 0.5f*qf);
  }
}

// ---- suffix scan over t (64k independent scans) + fused objective (ident)
__global__ __launch_bounds__(256) void k_scan(
    const float* __restrict__ TGT, const float* __restrict__ WGT,
    const float* __restrict__ U, float* __restrict__ TL,
    const int* __restrict__ FLG, float* __restrict__ PART_S)
{
  const int tid = threadIdx.x;
  const int bi = blockIdx.x*256 + tid;
  const int b = bi >> 7;
  const bool id = (*FLG != 0);
  const float w = WGT[b];
  float lst = TGT[bi];
  float obj = 0.f;
  if (id) { const float d = lst + U[(size_t)NS*(BB*DD) + bi]; obj = w*d*d; }
#pragma unroll 4
  for (int t = NS; t >= 1; --t) {
    const float v = TL[(size_t)t*(BB*DD) + bi];
    if (!id) TL[(size_t)t*(BB*DD) + bi] = lst;   // LST[t]
    lst += v;
    if (id) { const float d = lst + U[(size_t)(t-1)*(BB*DD) + bi]; obj += w*d*d; }
  }
  if (!id) TL[bi] = lst;                          // LST[0]
  __shared__ float r4[4];
  const float s = wave_red(obj);
  if ((tid & 63) == 0) r4[tid >> 6] = s;
  __syncthreads();
  if (tid == 0) PART_S[blockIdx.x] = id ? (r4[0]+r4[1]+r4[2]+r4[3]) : 0.f;
}

// ---- general-sigma objective (no-op when sigma == I)
__global__ __launch_bounds__(256) void k_obj(
    const float* __restrict__ SG2row, const float* __restrict__ TL,
    const float* __restrict__ U, const float* __restrict__ WGT,
    const int* __restrict__ FLG, float* __restrict__ PART_O)
{
  const int blk = blockIdx.x;
  if (*FLG != 0) { if (threadIdx.x == 0) PART_O[blk] = 0.f; return; }
  const int t = blk >> 6, bg = blk & 63;
  __shared__ __align__(16) float ls[8][132];
  __shared__ __align__(16) float us[8][128];
  __shared__ __align__(16) float pD[2][8][128];
  __shared__ float wg[8];
  __shared__ float r4[4];
  const int tid = threadIdx.x;
  const int i = tid & 127, h = tid >> 7;
  for (int idx = tid; idx < 8*128; idx += 256) {
    const int rr = idx >> 7, k = idx & 127;
    ls[rr][k] = TL[(size_t)t*(BB*DD) + (size_t)(bg*8+rr)*DD + k];
    us[rr][k] = U [(size_t)t*(BB*DD) + (size_t)(bg*8+rr)*DD + k];
  }
  if (tid < 8) wg[tid] = WGT[bg*8 + tid];
  __syncthreads();
  const float* grow = SG2row + i*128 + h*64;
#pragma unroll
  for (int rr = 0; rr < 8; ++rr) {
    float a = 0.f;
#pragma unroll
    for (int it = 0; it < 16; ++it) {
      float4 gv = *(const float4*)(grow + it*4);
      float4 l4 = *(const float4*)&ls[rr][h*64 + it*4];
      a = fma4(gv, l4, a);
    }
    pD[h][rr][i] = a;
  }
  __syncthreads();
  float obj = 0.f;
#pragma unroll
  for (int p = 0; p < 4; ++p) {
    const int rr = h*4 + p;
    const float d = pD[0][rr][i] + pD[1][rr][i] + us[rr][i];
    obj += wg[rr]*d*d;
  }
  const float s = wave_red(obj);
  if ((tid & 63) == 0) r4[tid >> 6] = s;
  __syncthreads();
  if (tid == 0) PART_O[blk] = r4[0]+r4[1]+r4[2]+r4[3];
}

__global__ __launch_bounds__(256) void k_fin(
    const float* __restrict__ PART_S, const float* __restrict__ PART_O,
    float* __restrict__ out)
{
  const int tid = threadIdx.x;
  float s = PART_S[tid];
  for (int idx = tid; idx < NPO; idx += 256) s += PART_O[idx];
  __shared__ float r4[4];
  const float v = wave_red(s);
  if ((tid & 63) == 0) r4[tid >> 6] = v;
  __syncthreads();
  if (tid == 0) out[0] = (r4[0]+r4[1]+r4[2]+r4[3]) * (1.0f/((float)(NS+1)*(float)BB));
}

extern "C" void kernel_launch(void* const* d_in, const int* in_sizes, int n_in,
                              void* d_out, int out_size, void* d_ws, size_t ws_size,
                              hipStream_t stream) {
  (void)in_sizes; (void)n_in; (void)out_size; (void)ws_size;
  const float* x0     = (const float*)d_in[0];
  const float* sigma  = (const float*)d_in[1];
  const float* A      = (const float*)d_in[2];
  const float* P      = (const float*)d_in[3];
  const float* Q      = (const float*)d_in[4];
  const float* W1     = (const float*)d_in[5];
  const float* b1     = (const float*)d_in[6];
  const float* W2     = (const float*)d_in[7];
  const float* b2     = (const float*)d_in[8];
  const float* noises = (const float*)d_in[9];

  float* ws = (float*)d_ws;
  const size_t SL = (size_t)BB*DD;         // 65536 per time slice
  float* TL     = ws;                       // (NS+1) slices: TERM then LST (aliased)
  float* U      = TL + (size_t)(NS+1)*SL;   // (NS+1) slices of controls
  float* TGT    = U  + (size_t)(NS+1)*SL;
  float* WGT    = TGT + SL;
  float* W1Tt   = WGT + BB;
  float* W1Tx   = W1Tt + HH;
  float* W2T    = W1Tx + (size_t)HH*DD;
  float* M2row  = W2T + (size_t)DD*HH;
  float* SG2row = M2row + (size_t)DD*DD;
  float* SIT    = SG2row + (size_t)DD*DD;
  float* AUG    = SIT + (size_t)DD*DD;
  float* PART_S = AUG + (size_t)DD*256;
  float* PART_O = PART_S + 256;
  int*   FLG    = (int*)(PART_O + NPO);
  float* out    = (float*)d_out;

  k_pre1<<<1, 256, 0, stream>>>(sigma, SIT, AUG, FLG);
  k_pre2<<<64, 256, 0, stream>>>(W1, W2, A, sigma, SIT, FLG,
                                 W1Tt, W1Tx, W2T, M2row, SG2row);
  k_rollout<<<NBLK, TPB, 0, stream>>>(x0, sigma, W1Tt, W1Tx, W2T, b1, b2, noises,
                                      A, P, Q, M2row, SG2row, FLG, U, TL, TGT, WGT);
  k_scan<<<(BB*DD)/256, 256, 0, stream>>>(TGT, WGT, U, TL, FLG, PART_S);
  k_obj<<<NPO, 256, 0, stream>>>(SG2row, TL, U, WGT, FLG, PART_O);
  k_fin<<<1, 256, 0, stream>>>(PART_S, PART_O, out);
}

// Round 3
// 2707.231 us; speedup vs baseline: 3.3620x; 1.0061x over previous
//
#include <hip/hip_runtime.h>
#include <math.h>

#define DD 128
#define HH 256
#define NS 300
#define BB 512
#define NBLK 256   // rollout blocks (2 rows each)
#define TPB 512
#define NPO (301*64)

// Dynamic-LDS float offsets for k_rollout
#define OFF_W1Q   0        // 8192 float4 = 32768 floats: [k4][hj]
#define OFF_XS    32768    // [2][128]
#define OFF_HS    33024    // [2][256]
#define OFF_WV    33536    // [2][128]
#define OFF_P2    33792    // [2][2][256]  (alias: general pUs2)
#define OFF_P4    34816    // [4][2][128]  (alias: general pNs2)
#define OFF_PM3   35840    // 3 x [4][2][128]
#define OFF_NOI   38912    // [2][128] (general only)
#define OFF_NVS   39168    // [2][128] (general; aliased as uu after D3)
#define OFF_RED   39424    // 16
#define SMEM_FLOATS 39440
#define SMEM_BYTES (SMEM_FLOATS*4)

__device__ __forceinline__ float tsf(int t){ return (float)((double)t*(1.0/(double)NS)); }

__device__ __forceinline__ float wave_red(float v){
#pragma unroll
  for(int o=32;o>0;o>>=1) v += __shfl_down(v,o);
  return v;
}
__device__ __forceinline__ float fma4(float4 a, float4 b, float acc){
  acc = fmaf(a.x,b.x,acc); acc = fmaf(a.y,b.y,acc);
  acc = fmaf(a.z,b.z,acc); acc = fmaf(a.w,b.w,acc); return acc;
}

// ---- pre1: identity flag + (general) Gauss-Jordan inverse -> SIT = sigma^-T
__global__ __launch_bounds__(256) void k_pre1(
    const float* __restrict__ sigma,
    float* __restrict__ SIT, float* __restrict__ AUG, int* __restrict__ FLG)
{
  const int j = threadIdx.x;
  __shared__ int s_ok; __shared__ int s_p; __shared__ float s_fac[DD];
  if (j == 0) s_ok = 1;
  __syncthreads();
  bool ok = true;
  for (int idx = j; idx < DD*DD; idx += 256) {
    const int r = idx >> 7, c = idx & 127;
    if (sigma[idx] != (r==c ? 1.f : 0.f)) ok = false;
  }
  if (!ok) s_ok = 0;
  __syncthreads();
  const bool ident = (s_ok != 0);
  if (j == 0) *FLG = ident ? 1 : 0;
  if (ident) {
    for (int idx = j; idx < DD*DD; idx += 256) {
      const int r = idx >> 7, c = idx & 127;
      SIT[idx] = (r==c) ? 1.f : 0.f;
    }
    return;
  }
  for (int idx = j; idx < DD*256; idx += 256) {
    const int r = idx >> 8, c = idx & 255;
    AUG[idx] = (c < DD) ? sigma[r*DD + c] : ((c-DD)==r ? 1.f : 0.f);
  }
  __syncthreads();
  for (int c = 0; c < DD; ++c) {
    if (j == 0) {
      int p = c; float best = fabsf(AUG[c*256 + c]);
      for (int r2 = c+1; r2 < DD; ++r2) {
        const float v = fabsf(AUG[r2*256 + c]);
        if (v > best) { best = v; p = r2; }
      }
      s_p = p;
    }
    __syncthreads();
    const int p = s_p;
    if (p != c) {
      const float tmp = AUG[c*256 + j];
      AUG[c*256 + j] = AUG[p*256 + j];
      AUG[p*256 + j] = tmp;
    }
    __syncthreads();
    const float pd = AUG[c*256 + c];
    const float rowv = AUG[c*256 + j];
    __syncthreads();
    AUG[c*256 + j] = rowv / pd;
    if (j < DD) s_fac[j] = (j == c) ? 0.f : AUG[j*256 + c];
    __syncthreads();
    const float prj = AUG[c*256 + j];
    for (int r2 = 0; r2 < DD; ++r2) {
      if (r2 != c) AUG[r2*256 + j] -= s_fac[r2] * prj;
    }
    __syncthreads();
  }
  for (int idx = j; idx < DD*DD; idx += 256) {
    const int j2 = idx >> 7, k = idx & 127;
    SIT[idx] = AUG[k*256 + DD + j2];
  }
}

// ---- pre2: M2 rows (-A @ sigma^-T) + sigma^T rows
__global__ __launch_bounds__(256) void k_pre2(
    const float* __restrict__ A, const float* __restrict__ sigma,
    const float* __restrict__ SIT, const int* __restrict__ FLG,
    float* __restrict__ M2row, float* __restrict__ SG2row)
{
  const int g = blockIdx.x*256 + threadIdx.x;
  const int gs = gridDim.x*256;
  const bool ident = (*FLG != 0);
  for (int idx = g; idx < DD*DD; idx += gs) {
    const int i2 = idx >> 7, k = idx & 127;
    SG2row[idx] = sigma[k*DD + i2];
    float m;
    if (ident) m = -A[idx];
    else {
      float acc = 0.f;
      for (int j = 0; j < DD; ++j) acc = fmaf(A[i2*DD + j], SIT[j*DD + k], acc);
      m = -acc;
    }
    M2row[idx] = m;
  }
}

// ---- rollout: 256 blocks x 512 threads, 2 trajectories per block.
// W1 lives in LDS; W2/A/P/M2 row-segments live in registers.
__global__ __launch_bounds__(TPB, 2) void k_rollout(
    const float* __restrict__ x0, const float* __restrict__ sigma,
    const float* __restrict__ W1, const float* __restrict__ b1,
    const float* __restrict__ W2, const float* __restrict__ b2,
    const float* __restrict__ noises,
    const float* __restrict__ Am, const float* __restrict__ Pm,
    const float* __restrict__ Qm,
    const float* __restrict__ M2row, const float* __restrict__ SG2row,
    const int* __restrict__ FLG,
    float* __restrict__ U, float* __restrict__ TL,
    float* __restrict__ TGT, float* __restrict__ WGT)
{
  extern __shared__ float sm[];
  float4* W1q = (float4*)(sm + OFF_W1Q);    // [k4*256 + hj]
  float*  xs  = sm + OFF_XS;                // [r*128 + i]
  float*  hs  = sm + OFF_HS;                // [r*256 + hj]
  float*  wv  = sm + OFF_WV;                // [r*128 + i]
  float*  p2  = sm + OFF_P2;                // [hg*512 + r*256 + hj]
  float*  p4  = sm + OFF_P4;                // [q*256 + r*128 + i]
  float*  pm3 = sm + OFF_PM3;               // pA | pP | pM, each [q*256 + r*128 + i]
  float*  noi = sm + OFF_NOI;               // general only
  float*  nvu = sm + OFF_NVS;               // general: nvs, then uu
  float*  red = sm + OFF_RED;
  float4* xs4 = (float4*)xs;                // row stride 32
  float4* hs4 = (float4*)hs;                // row stride 64
  float4* wv4 = (float4*)wv;                // row stride 32
  float4* nvu4= (float4*)nvu;
  float4* noi4= (float4*)noi;
  float*  pA = pm3, *pP = pm3 + 1024, *pM = pm3 + 2048;

  const int tid = threadIdx.x;
  const int hj = tid & 255, hg = tid >> 8;   // layer-1 mapping
  const int i = tid & 127, q = tid >> 7;     // layer-2 / matvec mapping
  const int wid = tid >> 6;
  const int b0 = blockIdx.x * 2;
  const bool ident = (*FLG != 0);

  // --- prologue: LDS W1 (k-quads) + register weights
  for (int idx = tid; idx < 8192; idx += TPB) {
    const int k4 = idx >> 8, h = idx & 255;
    float4 w;
    w.x = W1[(4*k4 + 1)*HH + h];
    w.y = W1[(4*k4 + 2)*HH + h];
    w.z = W1[(4*k4 + 3)*HH + h];
    w.w = W1[(4*k4 + 4)*HH + h];
    W1q[idx] = w;
  }
  const float w1t = (hg == 0) ? W1[hj] : 0.f;  // time-row weight
  const float b1c = b1[hj];
  const float b2i = b2[i];

  float4 w2r[16], ar[8], pr[8], mr[8];
#pragma unroll
  for (int m = 0; m < 16; ++m) {
    const int k = q*64 + 4*m;
    w2r[m] = make_float4(W2[(k+0)*DD+i], W2[(k+1)*DD+i], W2[(k+2)*DD+i], W2[(k+3)*DD+i]);
  }
#pragma unroll
  for (int m = 0; m < 8; ++m) {
    ar[m] = *(const float4*)(Am    + i*DD + q*32 + 4*m);
    pr[m] = *(const float4*)(Pm    + i*DD + q*32 + 4*m);
    mr[m] = *(const float4*)(M2row + i*DD + q*32 + 4*m);
  }
  if (tid < DD) { const float v = x0[tid]; xs[tid] = v; xs[128 + tid] = v; }

  float lwloc = 0.f;
  float u_reg = 0.f, nz = 0.f;

  for (int t = 0; t <= NS; ++t) {
    __syncthreads();                                   // [A] xs (and W1q) ready
    const float t0 = tsf(t);
    const float dt = tsf(t+1) - t0;
    const float sdt = sqrtf(dt);
    nz = 0.f;
    if (q < 2 && t < NS) {
      nz = noises[((size_t)t*BB + b0 + q)*DD + i];
      if (!ident) noi[q*128 + i] = nz;
    }
    // --- MLP layer 1: thread (hj, hg) half-dot, both rows
    float a0 = t0*w1t, a1 = t0*w1t;
#pragma unroll
    for (int m = 0; m < 16; ++m) {
      const float4 w  = W1q[(hg*16 + m)*256 + hj];
      const float4 x0v = xs4[hg*16 + m];
      const float4 x1v = xs4[32 + hg*16 + m];
      a0 = fma4(w, x0v, a0); a1 = fma4(w, x1v, a1);
    }
    p2[hg*512 + hj] = a0; p2[hg*512 + 256 + hj] = a1;
    __syncthreads();                                   // [B]
    {
      const int rr = tid >> 8, cc = tid & 255;
      hs[rr*256 + cc] = tanhf(p2[rr*256 + cc] + p2[512 + rr*256 + cc] + b1c);
    }
    __syncthreads();                                   // [C]
    // --- MLP layer 2: register weights, quarter-dot, both rows
    a0 = 0.f; a1 = 0.f;
#pragma unroll
    for (int m = 0; m < 16; ++m) {
      const float4 h0 = hs4[q*16 + m];
      const float4 h1 = hs4[64 + q*16 + m];
      a0 = fma4(w2r[m], h0, a0); a1 = fma4(w2r[m], h1, a1);
    }
    p4[q*256 + i] = a0; p4[q*256 + 128 + i] = a1;
    __syncthreads();                                   // [D]
    if (ident) {
      if (q < 2) {
        const float nv = p4[q*128 + i] + p4[256 + q*128 + i]
                       + p4[512 + q*128 + i] + p4[768 + q*128 + i] + b2i;
        u_reg = -nv;
        U[((size_t)t*BB + b0 + q)*DD + i] = u_reg;
        wv[q*128 + i] = sdt*nz + dt*u_reg;
      }
    } else {
      if (q < 2) {
        nvu[q*128 + i] = p4[q*128 + i] + p4[256 + q*128 + i]
                       + p4[512 + q*128 + i] + p4[768 + q*128 + i] + b2i;
      }
      __syncthreads();                                 // [D2]
      // u = -nv @ sigma : partials over quarter (stream SG2row)
      float s0 = 0.f, s1 = 0.f;
#pragma unroll
      for (int m = 0; m < 8; ++m) {
        const float4 gv = *(const float4*)(SG2row + i*DD + q*32 + 4*m);
        const float4 n0 = nvu4[q*8 + m];
        const float4 n1 = nvu4[32 + q*8 + m];
        s0 = fma4(gv, n0, s0); s1 = fma4(gv, n1, s1);
      }
      pA[q*256 + i] = s0; pA[q*256 + 128 + i] = s1;
      __syncthreads();                                 // [D3]
      if (q < 2) {
        u_reg = -(pA[q*128 + i] + pA[256 + q*128 + i]
                + pA[512 + q*128 + i] + pA[768 + q*128 + i]);
        nvu[q*128 + i] = u_reg;                        // now uu
        U[((size_t)t*BB + b0 + q)*DD + i] = u_reg;
        wv[q*128 + i] = sdt*nz + dt*u_reg;
      }
    }
    if (t == NS) break;
    __syncthreads();                                   // [E] wv (and uu) ready
    // --- matvecs from register rows: A@x, P@x, M2@wv
    {
      float aA0=0,aA1=0,aP0=0,aP1=0,aM0=0,aM1=0;
#pragma unroll
      for (int m = 0; m < 8; ++m) {
        const float4 x0v = xs4[q*8 + m];
        const float4 x1v = xs4[32 + q*8 + m];
        const float4 w0v = wv4[q*8 + m];
        const float4 w1v = wv4[32 + q*8 + m];
        aA0 = fma4(ar[m], x0v, aA0); aA1 = fma4(ar[m], x1v, aA1);
        aP0 = fma4(pr[m], x0v, aP0); aP1 = fma4(pr[m], x1v, aP1);
        aM0 = fma4(mr[m], w0v, aM0); aM1 = fma4(mr[m], w1v, aM1);
      }
      pA[q*256 + i] = aA0; pA[q*256 + 128 + i] = aA1;
      pP[q*256 + i] = aP0; pP[q*256 + 128 + i] = aP1;
      pM[q*256 + i] = aM0; pM[q*256 + 128 + i] = aM1;
      if (!ident) {
        // u@sigma^T and n@sigma^T partials (stream sigma); reuse p2/p4 regions
        float su0=0,su1=0,sn0=0,sn1=0;
#pragma unroll
        for (int m = 0; m < 8; ++m) {
          const float4 sv = *(const float4*)(sigma + i*DD + q*32 + 4*m);
          const float4 u0 = nvu4[q*8 + m];
          const float4 u1 = nvu4[32 + q*8 + m];
          const float4 z0 = noi4[q*8 + m];
          const float4 z1 = noi4[32 + q*8 + m];
          su0 = fma4(sv,u0,su0); su1 = fma4(sv,u1,su1);
          sn0 = fma4(sv,z0,sn0); sn1 = fma4(sv,z1,sn1);
        }
        p2[q*256 + i] = su0; p2[q*256 + 128 + i] = su1;
        p4[q*256 + i] = sn0; p4[q*256 + 128 + i] = sn1;
      }
    }
    __syncthreads();                                   // [F]
    if (q < 2) {
      const float xo = xs[q*128 + i];
      const float xa = pA[q*128+i] + pA[256+q*128+i] + pA[512+q*128+i] + pA[768+q*128+i];
      const float yy = pP[q*128+i] + pP[256+q*128+i] + pP[512+q*128+i] + pP[768+q*128+i];
      const float mm = pM[q*128+i] + pM[256+q*128+i] + pM[512+q*128+i] + pM[768+q*128+i];
      float usv, nsv;
      if (ident) { usv = u_reg; nsv = nz; }
      else {
        usv = p2[q*128+i] + p2[256+q*128+i] + p2[512+q*128+i] + p2[768+q*128+i];
        nsv = p4[q*128+i] + p4[256+q*128+i] + p4[512+q*128+i] + p4[768+q*128+i];
      }
      TL[(size_t)(t+1)*(BB*DD) + (size_t)(b0 + q)*DD + i] = dt*yy + mm;
      xs[q*128 + i] = xo + (xa + usv)*dt + sdt*nsv;
      lwloc += sdt*u_reg*nz - dt*(0.5f*u_reg*u_reg + 0.5f*xo*yy);
    }
  }
  // --- epilogue: TGT = x_NS @ Q^T, WGT = exp(lw - 0.5 x^T Q x)
  {
    float g0 = 0.f, g1 = 0.f;
#pragma unroll
    for (int m = 0; m < 8; ++m) {
      const float4 qv  = *(const float4*)(Qm + i*DD + q*32 + 4*m);
      const float4 x0v = xs4[q*8 + m];
      const float4 x1v = xs4[32 + q*8 + m];
      g0 = fma4(qv, x0v, g0); g1 = fma4(qv, x1v, g1);
    }
    pA[q*256 + i] = g0; pA[q*256 + 128 + i] = g1;
  }
  __syncthreads();
  float qloc = 0.f;
  if (q < 2) {
    const float tt = pA[q*128+i] + pA[256+q*128+i] + pA[512+q*128+i] + pA[768+q*128+i];
    TGT[(b0 + q)*DD + i] = tt;
    qloc = xs[q*128 + i]*tt;
  }
  const float rq = wave_red(qloc);
  const float rl = wave_red(lwloc);
  if ((tid & 63) == 0) { red[wid] = rq; red[8 + wid] = rl; }
  __syncthreads();
  if (tid == 0 || tid == 128) {
    const int r = tid >> 7;
    const float qf = red[2*r] + red[2*r + 1];
    const float lw = red[8 + 2*r] + red[8 + 2*r + 1];
    WGT[b0 + r] = expf(lw - 0.5f*qf);
  }
}

// ---- suffix scan over t (64k independent scans) + fused objective (ident)
__global__ __launch_bounds__(256) void k_scan(
    const float* __restrict__ TGT, const float* __restrict__ WGT,
    const float* __restrict__ U, float* __restrict__ TL,
    const int* __restrict__ FLG, float* __restrict__ PART_S)
{
  const int tid = threadIdx.x;
  const int bi = blockIdx.x*256 + tid;
  const int b = bi >> 7;
  const bool id = (*FLG != 0);
  const float w = WGT[b];
  float lst = TGT[bi];
  float obj = 0.f;
  if (id) { const float d = lst + U[(size_t)NS*(BB*DD) + bi]; obj = w*d*d; }
#pragma unroll 4
  for (int t = NS; t >= 1; --t) {
    const float v = TL[(size_t)t*(BB*DD) + bi];
    if (!id) TL[(size_t)t*(BB*DD) + bi] = lst;
    lst += v;
    if (id) { const float d = lst + U[(size_t)(t-1)*(BB*DD) + bi]; obj += w*d*d; }
  }
  if (!id) TL[bi] = lst;
  __shared__ float r4[4];
  const float s = wave_red(obj);
  if ((tid & 63) == 0) r4[tid >> 6] = s;
  __syncthreads();
  if (tid == 0) PART_S[blockIdx.x] = id ? (r4[0]+r4[1]+r4[2]+r4[3]) : 0.f;
}

// ---- general-sigma objective (no-op when sigma == I)
__global__ __launch_bounds__(256) void k_obj(
    const float* __restrict__ SG2row, const float* __restrict__ TL,
    const float* __restrict__ U, const float* __restrict__ WGT,
    const int* __restrict__ FLG, float* __restrict__ PART_O)
{
  const int blk = blockIdx.x;
  if (*FLG != 0) { if (threadIdx.x == 0) PART_O[blk] = 0.f; return; }
  const int t = blk >> 6, bg = blk & 63;
  __shared__ __align__(16) float ls[8][132];
  __shared__ __align__(16) float us[8][128];
  __shared__ __align__(16) float pD[2][8][128];
  __shared__ float wg[8];
  __shared__ float r4[4];
  const int tid = threadIdx.x;
  const int i = tid & 127, h = tid >> 7;
  for (int idx = tid; idx < 8*128; idx += 256) {
    const int rr = idx >> 7, k = idx & 127;
    ls[rr][k] = TL[(size_t)t*(BB*DD) + (size_t)(bg*8+rr)*DD + k];
    us[rr][k] = U [(size_t)t*(BB*DD) + (size_t)(bg*8+rr)*DD + k];
  }
  if (tid < 8) wg[tid] = WGT[bg*8 + tid];
  __syncthreads();
  const float* grow = SG2row + i*DD + h*64;
#pragma unroll
  for (int rr = 0; rr < 8; ++rr) {
    float a = 0.f;
#pragma unroll
    for (int it = 0; it < 16; ++it) {
      float4 gv = *(const float4*)(grow + it*4);
      float4 l4 = *(const float4*)&ls[rr][h*64 + it*4];
      a = fma4(gv, l4, a);
    }
    pD[h][rr][i] = a;
  }
  __syncthreads();
  float obj = 0.f;
#pragma unroll
  for (int p = 0; p < 4; ++p) {
    const int rr = h*4 + p;
    const float d = pD[0][rr][i] + pD[1][rr][i] + us[rr][i];
    obj += wg[rr]*d*d;
  }
  const float s = wave_red(obj);
  if ((tid & 63) == 0) r4[tid >> 6] = s;
  __syncthreads();
  if (tid == 0) PART_O[blk] = r4[0]+r4[1]+r4[2]+r4[3];
}

__global__ __launch_bounds__(256) void k_fin(
    const float* __restrict__ PART_S, const float* __restrict__ PART_O,
    float* __restrict__ out)
{
  const int tid = threadIdx.x;
  float s = PART_S[tid];
  for (int idx = tid; idx < NPO; idx += 256) s += PART_O[idx];
  __shared__ float r4[4];
  const float v = wave_red(s);
  if ((tid & 63) == 0) r4[tid >> 6] = v;
  __syncthreads();
  if (tid == 0) out[0] = (r4[0]+r4[1]+r4[2]+r4[3]) * (1.0f/((float)(NS+1)*(float)BB));
}

extern "C" void kernel_launch(void* const* d_in, const int* in_sizes, int n_in,
                              void* d_out, int out_size, void* d_ws, size_t ws_size,
                              hipStream_t stream) {
  (void)in_sizes; (void)n_in; (void)out_size; (void)ws_size;
  const float* x0     = (const float*)d_in[0];
  const float* sigma  = (const float*)d_in[1];
  const float* A      = (const float*)d_in[2];
  const float* P      = (const float*)d_in[3];
  const float* Q      = (const float*)d_in[4];
  const float* W1     = (const float*)d_in[5];
  const float* b1     = (const float*)d_in[6];
  const float* W2     = (const float*)d_in[7];
  const float* b2     = (const float*)d_in[8];
  const float* noises = (const float*)d_in[9];

  float* ws = (float*)d_ws;
  const size_t SL = (size_t)BB*DD;
  float* TL     = ws;
  float* U      = TL + (size_t)(NS+1)*SL;
  float* TGT    = U  + (size_t)(NS+1)*SL;
  float* WGT    = TGT + SL;
  float* M2row  = WGT + BB;
  float* SG2row = M2row + (size_t)DD*DD;
  float* SIT    = SG2row + (size_t)DD*DD;
  float* AUG    = SIT + (size_t)DD*DD;
  float* PART_S = AUG + (size_t)DD*256;
  float* PART_O = PART_S + 256;
  int*   FLG    = (int*)(PART_O + NPO);
  float* out    = (float*)d_out;

  static bool attr_set = false;
  if (!attr_set) {
    (void)hipFuncSetAttribute((const void*)k_rollout,
                              hipFuncAttributeMaxDynamicSharedMemorySize, SMEM_BYTES);
    attr_set = true;
  }

  k_pre1<<<1, 256, 0, stream>>>(sigma, SIT, AUG, FLG);
  k_pre2<<<32, 256, 0, stream>>>(A, sigma, SIT, FLG, M2row, SG2row);
  k_rollout<<<NBLK, TPB, SMEM_BYTES, stream>>>(x0, sigma, W1, b1, W2, b2, noises,
                                               A, P, Q, M2row, SG2row, FLG,
                                               U, TL, TGT, WGT);
  k_scan<<<(BB*DD)/256, 256, 0, stream>>>(TGT, WGT, U, TL, FLG, PART_S);
  k_obj<<<NPO, 256, 0, stream>>>(SG2row, TL, U, WGT, FLG, PART_O);
  k_fin<<<1, 256, 0, stream>>>(PART_S, PART_O, out);
}